// Round 2
// baseline (5176.278 us; speedup 1.0000x reference)
//
#include <hip/hip_runtime.h>
#include <math.h>

// ---------------- problem constants ----------------
#define TDIM  100      // channels AND time steps
#define HIN0  159
#define WDIM  132
#define KH    10
#define HIDN  100
#define G3    300      // 3*HID
#define FEATK 17424    // 132*132
#define BTOT  16
#define CHUNK 2        // batches per conv pipeline chunk (keeps ws ~138 MiB)

static __device__ __forceinline__ float sigmoidf_(float x) {
    return 1.f / (1.f + __expf(-x));
}

static __device__ __forceinline__ float bcastf(float v, int l) {
#if __has_builtin(__builtin_amdgcn_readlane)
    return __int_as_float(__builtin_amdgcn_readlane(__float_as_int(v), l));
#else
    return __shfl(v, l, 64);
#endif
}

// ---------------- conv: direct, 4 co per thread ----------------
// out[b,co,h,w] = bias[co] + sum_{ci,kh} in[b,ci,h+kh,w] * w[co,ci,kh]
// p = h*W + w  =>  in addr = base + ci*HIN*W + p + kh*W  (kernel is 10x1)
template<int HIN>
__global__ __launch_bounds__(256)
void conv_k(const float* __restrict__ in, const float* __restrict__ wt,
            const float* __restrict__ bias, float* __restrict__ out)
{
    constexpr int HOUT = HIN - KH + 1;
    const int p = blockIdx.x * 256 + threadIdx.x;
    if (p >= HOUT * WDIM) return;
    const int co0 = blockIdx.y * 4;
    const size_t zb = blockIdx.z;          // chunk-local batch

    const float* ip0 = in + zb * (size_t)TDIM * HIN * WDIM + p;
    const float* wp0 = wt + (size_t)co0 * (TDIM * KH);

    float a0 = 0.f, a1 = 0.f, a2 = 0.f, a3 = 0.f;
    for (int ci = 0; ci < TDIM; ++ci) {
        const float* ip = ip0 + ci * (HIN * WDIM);
        const float* wp = wp0 + ci * KH;   // wave-uniform -> scalar loads
        #pragma unroll
        for (int kh = 0; kh < KH; ++kh) {
            const float v = ip[kh * WDIM];
            a0 += v * wp[kh];
            a1 += v * wp[1 * TDIM * KH + kh];
            a2 += v * wp[2 * TDIM * KH + kh];
            a3 += v * wp[3 * TDIM * KH + kh];
        }
    }
    float* op = out + (zb * TDIM + co0) * (size_t)(HOUT * WDIM) + p;
    op[0 * HOUT * WDIM] = a0 + bias[co0 + 0];
    op[1 * HOUT * WDIM] = a1 + bias[co0 + 1];
    op[2 * HOUT * WDIM] = a2 + bias[co0 + 2];
    op[3 * HOUT * WDIM] = a3 + bias[co0 + 3];
}

// ---------------- xw init: xw[row, g] = b_ih[g] ----------------
__global__ __launch_bounds__(256)
void init_xw_k(const float* __restrict__ b_ih, float* __restrict__ xw)
{
    const int i = blockIdx.x * 256 + threadIdx.x;
    if (i < BTOT * TDIM * G3) xw[i] = b_ih[i % G3];
}

// ---------------- big GEMM: xw += gi @ w_ih^T ----------------
// A = gi [1600 x 17424] row-major; Bw = w_ih [300 x 17424] row-major (both K-contig).
// 64x64 tiles, BK=32, K split 4 ways across blockIdx.z, atomicAdd epilogue.
__global__ __launch_bounds__(256)
void gemm_xw(const float* __restrict__ A, const float* __restrict__ Bw,
             float* __restrict__ C)
{
    constexpr int M = BTOT * TDIM;        // 1600
    constexpr int N = G3;                 // 300
    constexpr int K = FEATK;              // 17424
    constexpr int BK = 32;
    constexpr int NCH = (K + BK - 1) / BK;   // 545
    constexpr int SEG = (NCH + 3) / 4;       // 137

    __shared__ float As[BK][68];   // [k][m], +4 pad keeps 16B alignment, tames conflicts
    __shared__ float Bs[BK][68];   // [k][n]

    const int tid = threadIdx.x;
    const int n0  = blockIdx.x * 64;
    const int m0  = blockIdx.y * 64;
    const int kc0 = blockIdx.z * SEG;
    const int kc1 = min(NCH, kc0 + SEG);
    const int ty  = tid >> 4, tx = tid & 15;

    float acc[4][4] = {{0.f}};

    for (int kc = kc0; kc < kc1; ++kc) {
        const int k0 = kc * BK;
        #pragma unroll
        for (int l = 0; l < 2; ++l) {
            const int idx = tid + l * 256;
            const int r   = idx >> 3;           // 0..63 (row within tile)
            const int c4  = (idx & 7) << 2;     // 0..28 (k within chunk, x4)
            float4 va = make_float4(0.f, 0.f, 0.f, 0.f);
            float4 vb = make_float4(0.f, 0.f, 0.f, 0.f);
            const bool kok = (k0 + c4 + 3) < K;     // K%4==0 -> float4 all-or-nothing
            if (kok && (m0 + r) < M)
                va = *reinterpret_cast<const float4*>(A + (size_t)(m0 + r) * K + k0 + c4);
            if (kok && (n0 + r) < N)
                vb = *reinterpret_cast<const float4*>(Bw + (size_t)(n0 + r) * K + k0 + c4);
            As[c4 + 0][r] = va.x; As[c4 + 1][r] = va.y;
            As[c4 + 2][r] = va.z; As[c4 + 3][r] = va.w;
            Bs[c4 + 0][r] = vb.x; Bs[c4 + 1][r] = vb.y;
            Bs[c4 + 2][r] = vb.z; Bs[c4 + 3][r] = vb.w;
        }
        __syncthreads();
        #pragma unroll 8
        for (int k = 0; k < BK; ++k) {
            const float4 av = *reinterpret_cast<const float4*>(&As[k][ty * 4]);
            const float4 bv = *reinterpret_cast<const float4*>(&Bs[k][tx * 4]);
            const float ar[4] = {av.x, av.y, av.z, av.w};
            const float br[4] = {bv.x, bv.y, bv.z, bv.w};
            #pragma unroll
            for (int i = 0; i < 4; ++i)
                #pragma unroll
                for (int j = 0; j < 4; ++j)
                    acc[i][j] += ar[i] * br[j];
        }
        __syncthreads();
    }

    #pragma unroll
    for (int i = 0; i < 4; ++i) {
        const int row = m0 + ty * 4 + i;
        if (row < M) {
            #pragma unroll
            for (int j = 0; j < 4; ++j) {
                const int col = n0 + tx * 4 + j;
                if (col < N) atomicAdd(&C[(size_t)row * N + col], acc[i][j]);
            }
        }
    }
}

// ---------------- GRU scan: one block per batch ----------------
// Threads 0..299 each own one row of w_hh in registers (constant across steps).
// h broadcast per k via readlane from two wave-resident registers.
//
// CORRECTNESS-CRITICAL: the h_s snapshot loads and the readlane MAC loop run
// UNCONDITIONALLY (full exec mask in every wave). If they were guarded by
// `if (tid < G3)`, the compiler can sink the LDS loads into the divergent
// branch, leaving lanes 44..63 of wave 4 with undefined hlo registers that
// v_readlane then reads (readlane ignores exec) -> garbage gh for gate rows
// 256..299. Only the gh_s WRITE is guarded. wreg/bh use a clamped row index
// so no thread holds undefined registers.
__global__ __launch_bounds__(320)
void gru_k(const float* __restrict__ xw, const float* __restrict__ w_hh,
           const float* __restrict__ b_hh, float* __restrict__ gout)
{
    __shared__ float h_s[128];     // 100 live + zero padding for hhi reads
    __shared__ float gh_s[G3];

    const int tid = threadIdx.x;
    const int b   = blockIdx.x;

    const int rowc = (tid < G3) ? tid : (G3 - 1);   // clamped: all regs defined
    const float bh = b_hh[rowc];
    float wreg[HIDN];
    #pragma unroll
    for (int k = 0; k < HIDN; ++k) wreg[k] = w_hh[(size_t)rowc * HIDN + k];

    if (tid < 128) h_s[tid] = 0.f;
    __syncthreads();

    const int lane = tid & 63;
    for (int t = 0; t < TDIM; ++t) {
        // full-exec snapshot: every lane of every wave loads its h element
        const float hlo = h_s[lane];
        const float hhi = h_s[64 + lane];
        // full-exec MAC: lanes with tid>=G3 compute a harmless duplicate
        float acc = bh;
        #pragma unroll
        for (int k = 0; k < 64; ++k)       acc += wreg[k] * bcastf(hlo, k);
        #pragma unroll
        for (int k = 64; k < HIDN; ++k)    acc += wreg[k] * bcastf(hhi, k - 64);
        if (tid < G3) gh_s[tid] = acc;
        __syncthreads();
        if (tid < HIDN) {
            const float* xwt = xw + ((size_t)b * TDIM + t) * G3;
            const float hp = h_s[tid];
            const float r  = sigmoidf_(xwt[tid]            + gh_s[tid]);
            const float z  = sigmoidf_(xwt[HIDN + tid]     + gh_s[HIDN + tid]);
            const float n  = tanhf(xwt[2 * HIDN + tid] + r * gh_s[2 * HIDN + tid]);
            const float hn = (1.f - z) * n + z * hp;
            h_s[tid] = hn;
            gout[((size_t)b * TDIM + t) * HIDN + tid] = hn;
        }
        __syncthreads();
    }
}

// ---------------- output heads ----------------
__global__ __launch_bounds__(256)
void heads_k(const float* __restrict__ g,
             const float* __restrict__ wy1, const float* __restrict__ by1,
             const float* __restrict__ wy2, const float* __restrict__ by2,
             float* __restrict__ out)
{
    constexpr int NY1 = BTOT * TDIM * 14;   // 22400
    constexpr int NY2 = BTOT * TDIM * 3;    // 4800
    const int idx = blockIdx.x * 256 + threadIdx.x;
    if (idx < NY1) {
        const int row = idx / 14, c = idx - row * 14;
        const float* gr = g + (size_t)row * HIDN;
        const float* wr = wy1 + c * HIDN;
        float acc = by1[c];
        for (int k = 0; k < HIDN; ++k) acc += gr[k] * wr[k];
        out[idx] = sigmoidf_(acc);
    } else if (idx < NY1 + NY2) {
        const int j = idx - NY1;
        const int row = j / 3, c = j - row * 3;
        const float* gr = g + (size_t)row * HIDN;
        const float* wr = wy2 + c * HIDN;
        float acc = by2[c];
        for (int k = 0; k < HIDN; ++k) acc += gr[k] * wr[k];
        out[NY1 + row * 3 + c] = tanhf(acc) * 10.f;
    }
}

// ---------------- launch ----------------
extern "C" void kernel_launch(void* const* d_in, const int* in_sizes, int n_in,
                              void* d_out, int out_size, void* d_ws, size_t ws_size,
                              hipStream_t stream)
{
    (void)in_sizes; (void)n_in; (void)out_size; (void)ws_size;
    const float* x    = (const float*)d_in[0];
    const float* w1   = (const float*)d_in[1];
    const float* bc1  = (const float*)d_in[2];
    const float* w2   = (const float*)d_in[3];
    const float* bc2  = (const float*)d_in[4];
    const float* w3   = (const float*)d_in[5];
    const float* bc3  = (const float*)d_in[6];
    const float* w_ih = (const float*)d_in[7];
    const float* w_hh = (const float*)d_in[8];
    const float* b_ih = (const float*)d_in[9];
    const float* b_hh = (const float*)d_in[10];
    const float* wy1  = (const float*)d_in[11];
    const float* by1  = (const float*)d_in[12];
    const float* wy2  = (const float*)d_in[13];
    const float* by2  = (const float*)d_in[14];
    float* out = (float*)d_out;

    // workspace layout (floats):
    //   c1: CHUNK*100*150*132 = 3,960,000
    //   c2: CHUNK*100*141*132 = 3,722,400
    //   gi: 16*100*17424      = 27,878,400   (full, feeds one big GEMM)
    //   xw: 16*100*300        = 480,000
    //   g : 16*100*100        = 160,000      -> total ~138.1 MiB
    float* ws = (float*)d_ws;
    float* c1 = ws;
    float* c2 = c1 + (size_t)CHUNK * TDIM * 150 * WDIM;
    float* gi = c2 + (size_t)CHUNK * TDIM * 141 * WDIM;
    float* xw = gi + (size_t)BTOT * TDIM * FEATK;
    float* g  = xw + (size_t)BTOT * TDIM * G3;

    for (int bb = 0; bb < BTOT; bb += CHUNK) {
        conv_k<159><<<dim3((150 * WDIM + 255) / 256, TDIM / 4, CHUNK), 256, 0, stream>>>(
            x + (size_t)bb * TDIM * HIN0 * WDIM, w1, bc1, c1);
        conv_k<150><<<dim3((141 * WDIM + 255) / 256, TDIM / 4, CHUNK), 256, 0, stream>>>(
            c1, w2, bc2, c2);
        conv_k<141><<<dim3((132 * WDIM + 255) / 256, TDIM / 4, CHUNK), 256, 0, stream>>>(
            c2, w3, bc3, gi + (size_t)bb * TDIM * FEATK);
    }
    init_xw_k<<<dim3((BTOT * TDIM * G3 + 255) / 256), 256, 0, stream>>>(b_ih, xw);
    gemm_xw<<<dim3(5, 25, 4), 256, 0, stream>>>(gi, w_ih, xw);
    gru_k<<<dim3(BTOT), 320, 0, stream>>>(xw, w_hh, b_hh, g);
    heads_k<<<dim3((27200 + 255) / 256), 256, 0, stream>>>(g, wy1, by1, wy2, by2, out);
}

// Round 3
// 1297.115 us; speedup vs baseline: 3.9906x; 3.9906x over previous
//
#include <hip/hip_runtime.h>
#include <math.h>

// ---------------- problem constants ----------------
#define TDIM  100
#define HIDN  100
#define G3    300
#define WD    132
#define CIP   104      // padded ci pitch (multiple of 8)
#define KP    1056     // padded conv K = 10*104 -> 33 ksteps of 32
#define NKC   33
#define GIK   17440    // padded FEAT (17424 -> 545 ksteps of 32)
#define GIN   320      // padded 3*HID
#define BTOT  16
#define BCH   4        // batches per conv chunk (ws ~120 MiB < 145 MiB proven)
#define INP0  (159 * WD)   // 20988

typedef float    f32x4 __attribute__((ext_vector_type(4)));
typedef _Float16 f16x8 __attribute__((ext_vector_type(8)));
typedef _Float16 f16x4 __attribute__((ext_vector_type(4)));

static __device__ __forceinline__ float sigmoidf_(float x) {
    return 1.f / (1.f + __expf(-x));
}
static __device__ __forceinline__ float bcastf(float v, int l) {
    return __int_as_float(__builtin_amdgcn_readlane(__float_as_int(v), l));
}

// ---------------- weight prepack: w[co][ci][kh] -> wp[112][KP], k = kh*104+ci ----------------
__global__ __launch_bounds__(256)
void prep_convw(const float* __restrict__ w, _Float16* __restrict__ wp)
{
    const int idx = blockIdx.x * 256 + threadIdx.x;
    if (idx >= 112 * KP) return;
    const int co = idx / KP, k = idx - co * KP;
    const int kh = k / CIP, ci = k - kh * CIP;
    float v = 0.f;
    if (co < 100 && ci < 100 && kh < 10)
        v = w[(co * 100 + ci) * 10 + kh];
    wp[idx] = (_Float16)v;
}

// ---------------- w_ih prepack: [300][17424] -> [GIN][GIK] fp16, zero pad ----------------
__global__ __launch_bounds__(256)
void prep_wih(const float* __restrict__ w_ih, _Float16* __restrict__ wihp)
{
    const int k = blockIdx.x * 256 + threadIdx.x;
    const int n = blockIdx.y;
    if (k >= GIK) return;
    const float v = (n < G3 && k < 17424) ? w_ih[(size_t)n * 17424 + k] : 0.f;
    wihp[(size_t)n * GIK + k] = (_Float16)v;
}

// ---------------- x transpose: x[b][ci][p] fp32 -> xT[b][p][CIP] fp16 (pad ci zeroed) -------
__global__ __launch_bounds__(256)
void transpose_x(const float* __restrict__ x, _Float16* __restrict__ xT)
{
    __shared__ __align__(16) _Float16 t[64][116];   // pitch 116: 8B-aligned rows, mild banking
    const int tid = threadIdx.x;
    const int p0  = blockIdx.x * 64;
    const int b   = blockIdx.y;
    const int pl  = tid & 63;
    const int p   = p0 + pl;
    t[tid >> 2][100 + (tid & 3)] = (_Float16)0.f;   // zero the ci pad (must be finite!)
    const float* xb = x + (size_t)b * 100 * INP0;
    #pragma unroll
    for (int i = 0; i < 25; ++i) {
        const int ci = (tid >> 6) + i * 4;
        const float v = (p < INP0) ? xb[(size_t)ci * INP0 + p] : 0.f;
        t[pl][ci] = (_Float16)v;
    }
    __syncthreads();
    _Float16* xTb = xT + (size_t)b * INP0 * CIP;
    #pragma unroll
    for (int i = 0; i < 7; ++i) {
        const int idx = tid + i * 256;
        if (idx < 64 * 26) {
            const int rr = idx / 26;
            const int c  = (idx - rr * 26) * 4;
            if (p0 + rr < INP0)
                *(f16x4*)(xTb + (size_t)(p0 + rr) * CIP + c) = *(const f16x4*)&t[rr][c];
        }
    }
}

// ---------------- conv as MFMA GEMM ----------------
// C[co,p] = bias[co] + sum_k wp[co][k] * actT[p + kh*132][ci],  k = kh*104+ci
// Block: co 0..111 (7 m-tiles) x p-tile of 128 (each wave: 2 n-tiles of 16).
// OUTT: write transposed [p][CIP] fp16 (feeds next conv); else gi[(b,co)][GIK].
template<int HIN, bool OUTT>
__global__ __launch_bounds__(256)
void conv_mfma(const _Float16* __restrict__ actT,   // [BCH][HIN*132][CIP]
               const _Float16* __restrict__ wp,     // [112][KP]
               const float*    __restrict__ bias,   // [100]
               _Float16* __restrict__ out)
{
    constexpr int HOUT = HIN - 9;
    constexpr int NP   = HOUT * WD;
    constexpr int INP  = HIN * WD;

    __shared__ __align__(16) _Float16 As[112][40];  // [co][k], pitch 40 -> 2-way banks
    __shared__ __align__(16) _Float16 Bs[128][40];  // [p ][k]

    const int tid = threadIdx.x;
    const int p0  = blockIdx.x * 128;
    const int b   = blockIdx.y;
    const _Float16* act_b = actT + (size_t)b * INP * CIP;

    f32x4 acc[7][2] = {};

    const int wv = tid >> 6;
    const int ln = tid & 15;
    const int lq = (tid & 63) >> 4;

    for (int kk = 0; kk < NKC; ++kk) {
        const int k0 = kk * 32;
        // stage A (weights): 448 x 16B
        int idx = tid;
        #pragma unroll
        for (int i = 0; i < 2; ++i, idx += 256) {
            if (idx < 448) {
                const int co = idx >> 2, run = idx & 3;
                *(uint4*)&As[co][run * 8] =
                    *(const uint4*)(wp + co * KP + k0 + run * 8);
            }
        }
        // stage B (input): 512 x 16B; 8-runs never cross a kh boundary (8|104)
        idx = tid;
        #pragma unroll
        for (int i = 0; i < 2; ++i, idx += 256) {
            const int pl = idx >> 2, run = idx & 3;
            const int k  = k0 + run * 8;
            const int kh = k / CIP;
            const int ci0 = k - kh * CIP;
            int row = p0 + pl + kh * WD;
            row = min(row, INP - 1);              // clamped rows feed discarded cols only
            *(uint4*)&Bs[pl][run * 8] =
                *(const uint4*)(act_b + (size_t)row * CIP + ci0);
        }
        __syncthreads();
        const f16x8 bf0 = *(const f16x8*)&Bs[(wv * 2 + 0) * 16 + ln][lq * 8];
        const f16x8 bf1 = *(const f16x8*)&Bs[(wv * 2 + 1) * 16 + ln][lq * 8];
        #pragma unroll
        for (int mt = 0; mt < 7; ++mt) {
            const f16x8 af = *(const f16x8*)&As[mt * 16 + ln][lq * 8];
            acc[mt][0] = __builtin_amdgcn_mfma_f32_16x16x32_f16(af, bf0, acc[mt][0], 0, 0, 0);
            acc[mt][1] = __builtin_amdgcn_mfma_f32_16x16x32_f16(af, bf1, acc[mt][1], 0, 0, 0);
        }
        __syncthreads();
    }

    // epilogue: D row = co-within-tile (quad*4+r), col = p-within-tile (lane&15)
    #pragma unroll
    for (int j = 0; j < 2; ++j) {
        const int p = p0 + (wv * 2 + j) * 16 + ln;
        if (p >= NP) continue;
        if (OUTT) {
            _Float16* orow = out + (size_t)b * NP * CIP + (size_t)p * CIP;
            #pragma unroll
            for (int mt = 0; mt < 7; ++mt) {
                const int co0 = mt * 16 + lq * 4;
                if (co0 < CIP) {                  // pad cols 100..103 get 0 (zero weights)
                    f16x4 v;
                    #pragma unroll
                    for (int r = 0; r < 4; ++r) {
                        const int co = co0 + r;
                        v[r] = (_Float16)(acc[mt][j][r] + (co < 100 ? bias[co] : 0.f));
                    }
                    *(f16x4*)(orow + co0) = v;
                }
            }
        } else {
            #pragma unroll
            for (int mt = 0; mt < 7; ++mt) {
                #pragma unroll
                for (int r = 0; r < 4; ++r) {
                    const int co = mt * 16 + lq * 4 + r;
                    if (co < 100)
                        out[((size_t)b * 100 + co) * GIK + p] =
                            (_Float16)(acc[mt][j][r] + bias[co]);
                }
            }
        }
    }
}

// ---------------- big GEMM: xw += gi @ wihp^T (fp16 MFMA, fp32 atomic epilogue) -------------
__global__ __launch_bounds__(256)
void gemm_mfma(const _Float16* __restrict__ A,   // gi [1600][GIK]
               const _Float16* __restrict__ B,   // wihp [GIN][GIK]
               float* __restrict__ C)            // xw [1600][300]
{
    constexpr int NKG = GIK / 32;    // 545
    constexpr int SEG = 69;          // 8 z-slices
    __shared__ __align__(16) _Float16 As[64][40];
    __shared__ __align__(16) _Float16 Bs[64][40];

    const int tid = threadIdx.x;
    const int n0  = blockIdx.x * 64;
    const int m0  = blockIdx.y * 64;
    const int k00 = blockIdx.z * SEG;
    const int k01 = min(NKG, k00 + SEG);

    const int wv = tid >> 6, ln = tid & 15, lq = (tid & 63) >> 4;
    const int r = tid >> 2, run = tid & 3;

    f32x4 acc[4] = {};

    for (int kk = k00; kk < k01; ++kk) {
        const int k0 = kk * 32;
        *(uint4*)&As[r][run * 8] = *(const uint4*)(A + (size_t)(m0 + r) * GIK + k0 + run * 8);
        *(uint4*)&Bs[r][run * 8] = *(const uint4*)(B + (size_t)(n0 + r) * GIK + k0 + run * 8);
        __syncthreads();
        const f16x8 af = *(const f16x8*)&As[wv * 16 + ln][lq * 8];
        #pragma unroll
        for (int nt = 0; nt < 4; ++nt) {
            const f16x8 bf = *(const f16x8*)&Bs[nt * 16 + ln][lq * 8];
            acc[nt] = __builtin_amdgcn_mfma_f32_16x16x32_f16(af, bf, acc[nt], 0, 0, 0);
        }
        __syncthreads();
    }
    #pragma unroll
    for (int nt = 0; nt < 4; ++nt) {
        const int n = n0 + nt * 16 + ln;
        if (n < G3) {
            const int m = m0 + wv * 16 + lq * 4;
            #pragma unroll
            for (int rr = 0; rr < 4; ++rr)
                atomicAdd(&C[(size_t)(m + rr) * G3 + n], acc[nt][rr]);
        }
    }
}

// ---------------- xw init: xw[row, g] = b_ih[g] ----------------
__global__ __launch_bounds__(256)
void init_xw_k(const float* __restrict__ b_ih, float* __restrict__ xw)
{
    const int i = blockIdx.x * 256 + threadIdx.x;
    if (i < BTOT * TDIM * G3) xw[i] = b_ih[i % G3];
}

// ---------------- GRU scan (verified in R2 — unchanged) ----------------
__global__ __launch_bounds__(320)
void gru_k(const float* __restrict__ xw, const float* __restrict__ w_hh,
           const float* __restrict__ b_hh, float* __restrict__ gout)
{
    __shared__ float h_s[128];
    __shared__ float gh_s[G3];

    const int tid = threadIdx.x;
    const int b   = blockIdx.x;

    const int rowc = (tid < G3) ? tid : (G3 - 1);
    const float bh = b_hh[rowc];
    float wreg[HIDN];
    #pragma unroll
    for (int k = 0; k < HIDN; ++k) wreg[k] = w_hh[(size_t)rowc * HIDN + k];

    if (tid < 128) h_s[tid] = 0.f;
    __syncthreads();

    const int lane = tid & 63;
    for (int t = 0; t < TDIM; ++t) {
        const float hlo = h_s[lane];          // full-exec snapshot (readlane hazard)
        const float hhi = h_s[64 + lane];
        float acc = bh;
        #pragma unroll
        for (int k = 0; k < 64; ++k)       acc += wreg[k] * bcastf(hlo, k);
        #pragma unroll
        for (int k = 64; k < HIDN; ++k)    acc += wreg[k] * bcastf(hhi, k - 64);
        if (tid < G3) gh_s[tid] = acc;
        __syncthreads();
        if (tid < HIDN) {
            const float* xwt = xw + ((size_t)b * TDIM + t) * G3;
            const float hp = h_s[tid];
            const float r  = sigmoidf_(xwt[tid]            + gh_s[tid]);
            const float z  = sigmoidf_(xwt[HIDN + tid]     + gh_s[HIDN + tid]);
            const float n  = tanhf(xwt[2 * HIDN + tid] + r * gh_s[2 * HIDN + tid]);
            const float hn = (1.f - z) * n + z * hp;
            h_s[tid] = hn;
            gout[((size_t)b * TDIM + t) * HIDN + tid] = hn;
        }
        __syncthreads();
    }
}

// ---------------- output heads ----------------
__global__ __launch_bounds__(256)
void heads_k(const float* __restrict__ g,
             const float* __restrict__ wy1, const float* __restrict__ by1,
             const float* __restrict__ wy2, const float* __restrict__ by2,
             float* __restrict__ out)
{
    constexpr int NY1 = BTOT * TDIM * 14;
    constexpr int NY2 = BTOT * TDIM * 3;
    const int idx = blockIdx.x * 256 + threadIdx.x;
    if (idx < NY1) {
        const int row = idx / 14, c = idx - row * 14;
        const float* gr = g + (size_t)row * HIDN;
        const float* wr = wy1 + c * HIDN;
        float acc = by1[c];
        for (int k = 0; k < HIDN; ++k) acc += gr[k] * wr[k];
        out[idx] = sigmoidf_(acc);
    } else if (idx < NY1 + NY2) {
        const int j = idx - NY1;
        const int row = j / 3, c = j - row * 3;
        const float* gr = g + (size_t)row * HIDN;
        const float* wr = wy2 + c * HIDN;
        float acc = by2[c];
        for (int k = 0; k < HIDN; ++k) acc += gr[k] * wr[k];
        out[NY1 + row * 3 + c] = tanhf(acc) * 10.f;
    }
}

// ---------------- launch ----------------
extern "C" void kernel_launch(void* const* d_in, const int* in_sizes, int n_in,
                              void* d_out, int out_size, void* d_ws, size_t ws_size,
                              hipStream_t stream)
{
    (void)in_sizes; (void)n_in; (void)out_size; (void)ws_size;
    const float* x    = (const float*)d_in[0];
    const float* w1   = (const float*)d_in[1];
    const float* bc1  = (const float*)d_in[2];
    const float* w2   = (const float*)d_in[3];
    const float* bc2  = (const float*)d_in[4];
    const float* w3   = (const float*)d_in[5];
    const float* bc3  = (const float*)d_in[6];
    const float* w_ih = (const float*)d_in[7];
    const float* w_hh = (const float*)d_in[8];
    const float* b_ih = (const float*)d_in[9];
    const float* b_hh = (const float*)d_in[10];
    const float* wy1  = (const float*)d_in[11];
    const float* by1  = (const float*)d_in[12];
    const float* wy2  = (const float*)d_in[13];
    const float* by2  = (const float*)d_in[14];
    float* out = (float*)d_out;

    // workspace carve-up (~120 MiB total; 145 MiB proven available in R2)
    char* wsp = (char*)d_ws;
    auto alloc = [&](size_t bytes) -> char* {
        char* p = wsp; wsp += (bytes + 255) & ~(size_t)255; return p;
    };
    _Float16* wp1  = (_Float16*)alloc((size_t)112 * KP * 2);
    _Float16* wp2  = (_Float16*)alloc((size_t)112 * KP * 2);
    _Float16* wp3  = (_Float16*)alloc((size_t)112 * KP * 2);
    _Float16* wihp = (_Float16*)alloc((size_t)GIN * GIK * 2);
    _Float16* xT   = (_Float16*)alloc((size_t)BCH * INP0 * CIP * 2);
    _Float16* c1T  = (_Float16*)alloc((size_t)BCH * 150 * WD * CIP * 2);
    _Float16* c2T  = (_Float16*)alloc((size_t)BCH * 141 * WD * CIP * 2);
    _Float16* gi   = (_Float16*)alloc((size_t)BTOT * TDIM * GIK * 2);
    float*    xw   = (float*)   alloc((size_t)BTOT * TDIM * G3 * 4);
    float*    g    = (float*)   alloc((size_t)BTOT * TDIM * HIDN * 4);

    prep_convw<<<(112 * KP + 255) / 256, 256, 0, stream>>>(w1, wp1);
    prep_convw<<<(112 * KP + 255) / 256, 256, 0, stream>>>(w2, wp2);
    prep_convw<<<(112 * KP + 255) / 256, 256, 0, stream>>>(w3, wp3);
    prep_wih<<<dim3((GIK + 255) / 256, GIN), 256, 0, stream>>>(w_ih, wihp);
    init_xw_k<<<(BTOT * TDIM * G3 + 255) / 256, 256, 0, stream>>>(b_ih, xw);

    for (int cb = 0; cb < BTOT; cb += BCH) {
        transpose_x<<<dim3((INP0 + 63) / 64, BCH), 256, 0, stream>>>(
            x + (size_t)cb * 100 * INP0, xT);
        conv_mfma<159, true><<<dim3(155, BCH), 256, 0, stream>>>(xT,  wp1, bc1, c1T);
        conv_mfma<150, true><<<dim3(146, BCH), 256, 0, stream>>>(c1T, wp2, bc2, c2T);
        conv_mfma<141, false><<<dim3(137, BCH), 256, 0, stream>>>(
            c2T, wp3, bc3, gi + (size_t)cb * TDIM * GIK);
    }
    gemm_mfma<<<dim3(5, 25, 8), 256, 0, stream>>>(gi, wihp, xw);
    gru_k<<<16, 320, 0, stream>>>(xw, w_hh, b_hh, g);
    heads_k<<<(27200 + 255) / 256, 256, 0, stream>>>(g, wy1, by1, wy2, by2, out);
}